// Round 1
// baseline (104.959 us; speedup 1.0000x reference)
//
#include <hip/hip_runtime.h>
#include <hip/hip_bf16.h>
#include <math.h>

// BasicBlockA via MFMA (bf16 in, fp32 accum). R13 = R12 + conflict-free h layout:
//   hsb was [px][48ch] (96-B rows): stage-2 ds_read_b128 lanes {n,n+4,n+8,n+12} differ
//   by 384 B = 0 mod 128 -> 4-way bank conflict on every read (and 4-way on h-writes).
//   Now hsb is [oct(6)][px(306)][8ch] (same 29376 B -> occupancy stays 5 blk/CU):
//   stage-2 A-frag octet read = (oct*NPX+px)*16 B, 16 lanes cover 256 contiguous bytes
//   -> every bank exactly 8 accesses per wave64 b128 = 8-cycle minimum, conflict-free.
//   Stage-1 h-writes become stride-16B b64s, bank-balanced (4 accesses/bank = 4-cy min).
// Stage 1 unchanged (transposed C[m=ch][n=px], mask from lane's own pixel).
// Layouts (m89/m91): A[m=lane&15][k=q*8+j], B[k=q*8+j][n=lane&15], C col=lane&15 row=q*4+reg.

typedef short bf16x8 __attribute__((ext_vector_type(8)));
typedef short bf16x4 __attribute__((ext_vector_type(4)));
typedef float f32x4  __attribute__((ext_vector_type(4)));

namespace {
constexpr int NC = 3, NH = 128, NW = 128;
constexpr int TS = 16;                        // output tile 16x16
constexpr int XRow = 20, XCol = 20;           // xs bf16 [20][20][4]
constexpr int NPX = 306;                      // h pixels: 17 rows x 18 cols (flat)
constexpr int NT  = 20;                       // stage-1 M-tiles (20*16 = 320 slots)
constexpr int W2OFF = 1536;                   // shorts: w1tab 3*64*8, w2tab 8*64*8
constexpr int WTN   = 1536 + 4096;            // 5632 shorts = 11264 B in d_ws
}

__device__ __forceinline__ float softplusf(float v) {
    return v > 20.f ? v : log1pf(expf(v));
}
__device__ __forceinline__ unsigned short f2bf(float v) {   // RNE (prep only)
    __hip_bfloat16 h = __float2bfloat16(v);
    return *reinterpret_cast<unsigned short*>(&h);
}
__device__ __forceinline__ unsigned short rne(float v) {    // manual RNE, cheap
    unsigned u = __float_as_uint(v);
    u += 0x7FFF + ((u >> 16) & 1);
    return (unsigned short)(u >> 16);
}

// w1tab [f(3)][lane(64)][8]: stage-1 A-frag; m=lane&15 -> channel ch=f*16+m (=l*3+i),
//   k=q*8+j -> ky=k>>4, kx=(k>>2)&3, chin=k&3 (kx==3 / chin==3 zero-pad).
// w2tab [mfma m(8)][lane(64)][8]: stage-2 B-frag, K-folded: k=m*32+q*8+j;
//   k<240: combo c=k/48 (ky=c>=3, kx=c-3*ky), ch=k%48 (l=ch/3, jj=ch%3);
//   column n = out channel (n>=3 or k>=240 -> zero).
__global__ void prep_weights(const float* __restrict__ w1, const float* __restrict__ c1,
                             const float* __restrict__ w2, const float* __restrict__ c2,
                             unsigned short* __restrict__ tab) {
    int e = blockIdx.x * 256 + threadIdx.x;
    if (e >= WTN) return;
    float v = 0.f;
    if (e < W2OFF) {
        int f = e >> 9, lane = (e >> 3) & 63, j = e & 7;
        int m = lane & 15, q = lane >> 4;
        int k = q * 8 + j;
        int ky = k >> 4, kx = (k >> 2) & 3, chin = k & 3;
        int ch = f * 16 + m;                 // output channel of stage 1 (= l*3+i)
        if (kx < 3 && chin < 3 && ch < 48) {
            int l = ch / 3, i = ch - l * 3;
            bool live = (ky == 0) || (kx == 0) || (kx == 1 && chin <= i);
            if (live) {
                int g = ((l * 3 + i) * 3 + chin) * 9 + ky * 3 + kx;
                v = (i == chin && ky == 1 && kx == 1) ? softplusf(c1[g]) : w1[g];
            }
        }
    } else {
        int e2 = e - W2OFF;
        int mf = e2 >> 9, lane = (e2 >> 3) & 63, j = e2 & 7;
        int n = lane & 15, q = lane >> 4;
        int k = mf * 32 + q * 8 + j;
        if (n < 3 && k < 240) {
            int c  = k / 48, ch = k - c * 48;
            int ky = (c >= 3) ? 1 : 0, kx = c - 3 * ky;
            int l = ch / 3, jj = ch - l * 3;
            bool live = (ky == 0) || (kx == 0) || (kx == 1 && jj <= n);
            if (live) {
                int g = ((l * 3 + n) * 3 + jj) * 9 + ky * 3 + kx;
                v = (n == jj && ky == 1 && kx == 1) ? softplusf(c2[g]) : w2[g];
            }
        }
    }
    tab[e] = f2bf(v);
}

__global__ __launch_bounds__(256, 5) void fused_mfma(
    const float* __restrict__ x, const float* __restrict__ bias1,
    const float* __restrict__ res, const unsigned short* __restrict__ tab,
    float* __restrict__ out)
{
    __shared__ __align__(16) unsigned short xsb[XRow * XCol * 4];  // 3200 B
    __shared__ __align__(16) unsigned short hsb[6 * NPX * 8];      // 29376 B, [oct][px][8]

    const int tid  = threadIdx.x;
    const int b    = blockIdx.z;
    const int py0  = blockIdx.y * TS;
    const int px0  = blockIdx.x * TS;
    const int lane = tid & 63;
    const int wv   = tid >> 6;
    const int n    = lane & 15;
    const int q    = lane >> 4;

    // ---- stage x tile fp32->bf16 packed [r][c][4] ----
    const float* xb = x + b * NC * NH * NW;
    #pragma unroll
    for (int it = 0; it < 2; ++it) {
        unsigned p = tid + it * 256;
        if (p < XRow * XCol) {
            unsigned r = p / XCol, c = p - r * XCol;
            int gy = (int)(py0 - 2 + r), gx = (int)(px0 - 2 + c);
            bool ok = ((unsigned)gy < NH) && ((unsigned)gx < NW);
            const float* sp = xb + gy * NW + gx;
            float v0 = ok ? sp[0]           : 0.f;
            float v1 = ok ? sp[NH * NW]     : 0.f;
            float v2 = ok ? sp[2 * NH * NW] : 0.f;
            unsigned short s[4] = {rne(v0), rne(v1), rne(v2), 0};
            *(bf16x4*)(xsb + p * 4) = *(const bf16x4*)s;
        }
    }

    float rg; { float rv = res[0]; rg = rv > 0.f ? rv : 0.f; }
    // bias for channels f*16 + q*4 + r (r=0..3), f=0..2 -- 16B-aligned float4 loads
    float4 b4[3];
    #pragma unroll
    for (int f = 0; f < 3; ++f) b4[f] = *(const float4*)(bias1 + f * 16 + q * 4);

    // stage-1 A-frags (weights): coalesced 16B global loads (L2-hot table)
    bf16x8 a1f0 = *(const bf16x8*)(tab + (0 * 64 + lane) * 8);
    bf16x8 a1f1 = *(const bf16x8*)(tab + (1 * 64 + lane) * 8);
    bf16x8 a1f2 = *(const bf16x8*)(tab + (2 * 64 + lane) * 8);

    __syncthreads();  // xsb ready

    // ---- stage 1: 20 flat-px M-tiles, waves round-robin (5 each) ----
    constexpr int OSTR = NPX * 8;             // shorts per channel-octet plane
    #pragma unroll 1
    for (int t = wv; t < NT; t += 4) {
        unsigned p  = t * 16 + n;                 // this lane's pixel (B column)
        unsigned pr = p / 18, pc = p - pr * 18;
        const unsigned short* bp =
            xsb + ((pr + (q >> 1)) * XCol + pc + ((q & 1) << 1)) * 4;
        bf16x4 lo = *(const bf16x4*)bp;
        bf16x4 hi = *(const bf16x4*)(bp + 4);
        bf16x8 bf;
        #pragma unroll
        for (int j = 0; j < 4; ++j) { bf[j] = lo[j]; bf[4 + j] = hi[j]; }
        f32x4 z = {0.f, 0.f, 0.f, 0.f};
        f32x4 c0 = __builtin_amdgcn_mfma_f32_16x16x32_bf16(a1f0, bf, z, 0, 0, 0);
        f32x4 c1 = __builtin_amdgcn_mfma_f32_16x16x32_bf16(a1f1, bf, z, 0, 0, 0);
        f32x4 c2 = __builtin_amdgcn_mfma_f32_16x16x32_bf16(a1f2, bf, z, 0, 0, 0);
        // mask for this pixel (h row pr-1, col pc-1 in image coords)
        float mk = (((unsigned)(py0 + (int)pr - 1) < NH) &&
                    ((unsigned)(px0 + (int)pc - 1) < NW)) ? 1.f : 0.f;
        if (p < NPX) {
            unsigned short s0[4], s1[4], s2[4];
            #pragma unroll
            for (int r = 0; r < 4; ++r) {
                float v0 = c0[r] + ((const float*)&b4[0])[r];
                float v1 = c1[r] + ((const float*)&b4[1])[r];
                float v2 = c2[r] + ((const float*)&b4[2])[r];
                v0 = (v0 > 0.f ? v0 : __expf(v0) - 1.f) * mk;
                v1 = (v1 > 0.f ? v1 : __expf(v1) - 1.f) * mk;
                v2 = (v2 > 0.f ? v2 : __expf(v2) - 1.f) * mk;
                s0[r] = rne(v0); s1[r] = rne(v1); s2[r] = rne(v2);
            }
            // channel ch = f*16 + q*4 + r -> octet = f*2 + (q>>1), intra = (q&1)*4
            unsigned short* hp = hsb + p * 8 + ((q & 1) << 2);
            *(bf16x4*)(hp + ((q >> 1) + 0) * OSTR) = *(const bf16x4*)s0;  // f=0
            *(bf16x4*)(hp + ((q >> 1) + 2) * OSTR) = *(const bf16x4*)s1;  // f=1
            *(bf16x4*)(hp + ((q >> 1) + 4) * OSTR) = *(const bf16x4*)s2;  // f=2
        }
    }

    // stage-2 B-frags (K-folded table): 8 coalesced 16B loads, before the barrier
    bf16x8 b2k[8];
    #pragma unroll
    for (int m = 0; m < 8; ++m)
        b2k[m] = *(const bf16x8*)(tab + W2OFF + (m * 64 + lane) * 8);

    // per-lane A-frag deltas (lane-constant across out rows), in [oct][px][8] layout
    int dlt[8];
    #pragma unroll
    for (int m = 0; m < 8; ++m) {
        int idx = m * 32 + q * 8;            // k-octet start for this lane
        int c   = idx / 48;                  // combo (compile-folds to cheap seq)
        int off = idx - c * 48;              // channel octet within combo (mult of 8)
        int ky  = (c >= 3) ? 1 : 0, kx = c - 3 * ky;
        // pad lanes (idx>=240): B cols zero, any in-bounds h data is fine
        dlt[m] = (idx < 240) ? ((off >> 3) * NPX + ky * 18 + kx) * 8 : 0;
    }

    __syncthreads();  // hsb ready

    // ---- stage 2: out row py, K=240 folded in 8 MFMAs, 4 accumulators ----
    float* ob = out + b * NC * NH * NW;
    #pragma unroll 1
    for (int s = 0; s < 4; ++s) {
        int py = wv + s * 4;                 // out row 0..15
        const unsigned short* hbase = hsb + (py * 18 + n) * 8;
        f32x4 acc[4];
        #pragma unroll
        for (int a = 0; a < 4; ++a) acc[a] = (f32x4){0.f, 0.f, 0.f, 0.f};
        #pragma unroll
        for (int m = 0; m < 8; ++m) {
            bf16x8 af = *(const bf16x8*)(hbase + dlt[m]);
            acc[m & 3] = __builtin_amdgcn_mfma_f32_16x16x32_bf16(af, b2k[m], acc[m & 3], 0, 0, 0);
        }
        if (n < 3) {                          // lanes with a real out channel
            f32x4 t0, t1, sum;
            #pragma unroll
            for (int r = 0; r < 4; ++r) {
                t0[r] = acc[0][r] + acc[1][r];
                t1[r] = acc[2][r] + acc[3][r];
                sum[r] = t0[r] + t1[r];
            }
            int gy = py0 + py;
            const float* xp = xb + n * NH * NW + gy * NW + px0;
            float*       op = ob + n * NH * NW + gy * NW + px0;
            float4 xv = *(const float4*)(xp + q * 4);
            float4 o;
            o.x = sum[0] * (1.f / 16.f) + rg * xv.x;
            o.y = sum[1] * (1.f / 16.f) + rg * xv.y;
            o.z = sum[2] * (1.f / 16.f) + rg * xv.z;
            o.w = sum[3] * (1.f / 16.f) + rg * xv.w;
            *(float4*)(op + q * 4) = o;
        }
    }
}

extern "C" void kernel_launch(void* const* d_in, const int* in_sizes, int n_in,
                              void* d_out, int out_size, void* d_ws, size_t ws_size,
                              hipStream_t stream) {
    (void)in_sizes; (void)n_in; (void)out_size; (void)ws_size;
    const float* x   = (const float*)d_in[0];
    const float* w1  = (const float*)d_in[1];
    const float* c1  = (const float*)d_in[2];
    const float* b1  = (const float*)d_in[3];
    const float* w2  = (const float*)d_in[4];
    const float* c2  = (const float*)d_in[5];
    const float* res = (const float*)d_in[6];
    float* out = (float*)d_out;
    unsigned short* tab = (unsigned short*)d_ws;   // 11264 B of swizzled bf16 weights

    hipLaunchKernelGGL(prep_weights, dim3((WTN + 255) / 256), dim3(256), 0, stream,
                       w1, c1, w2, c2, tab);
    hipLaunchKernelGGL(fused_mfma, dim3(NW / TS, NH / TS, 64), dim3(256), 0, stream,
                       x, b1, res, tab, out);
}

// Round 2
// 101.845 us; speedup vs baseline: 1.0306x; 1.0306x over previous
//
#include <hip/hip_runtime.h>
#include <hip/hip_bf16.h>
#include <math.h>

// BasicBlockA via MFMA (bf16 in, fp32 accum). R14 = R13 + stage-1 VALU trim:
//   (a) fp32->bf16 packing via v_cvt_pk_bf16_f32 (HW RNE, 1 op per 2 values) replacing
//       manual-RNE bit twiddling (~5 ops/value) in x-staging and the h epilogue.
//   (b) bias1 folded into the stage-1 MFMA: xsb pad channel = 1.0 (always, even for
//       out-of-image pixels -- zero-padding applies only to real x channels), and w1tab
//       slots (ky=0,kx=0,chin=3)/(ky=0,kx=1,chin=3) carry bf16(b) and b-bf16(b) (hi+lo
//       split keeps bias at ~fp32 precision). Removes 12 adds/tile + b4 loads.
// R13: hsb [oct(6)][px(306)][8ch] conflict-free layout (kept; LDS not the bottleneck
//   but layout is harmless). Stage-2 K-folded: 8 MFMAs per out row, 4 accumulators.
// Layouts (m89/m91): A[m=lane&15][k=q*8+j], B[k=q*8+j][n=lane&15], C col=lane&15 row=q*4+reg.

typedef short bf16x8 __attribute__((ext_vector_type(8)));
typedef short bf16x4 __attribute__((ext_vector_type(4)));
typedef float f32x4  __attribute__((ext_vector_type(4)));

namespace {
constexpr int NC = 3, NH = 128, NW = 128;
constexpr int TS = 16;                        // output tile 16x16
constexpr int XRow = 20, XCol = 20;           // xs bf16 [20][20][4]
constexpr int NPX = 306;                      // h pixels: 17 rows x 18 cols (flat)
constexpr int NT  = 20;                       // stage-1 M-tiles (20*16 = 320 slots)
constexpr int W2OFF = 1536;                   // shorts: w1tab 3*64*8, w2tab 8*64*8
constexpr int WTN   = 1536 + 4096;            // 5632 shorts = 11264 B in d_ws
}

__device__ __forceinline__ float softplusf(float v) {
    return v > 20.f ? v : log1pf(expf(v));
}
__device__ __forceinline__ unsigned short f2bf(float v) {   // RNE (prep only)
    __hip_bfloat16 h = __float2bfloat16(v);
    return *reinterpret_cast<unsigned short*>(&h);
}

// w1tab [f(3)][lane(64)][8]: stage-1 A-frag; m=lane&15 -> channel ch=f*16+m (=l*3+i),
//   k=q*8+j -> ky=k>>4, kx=(k>>2)&3, chin=k&3 (kx==3 zero-pad; chin==3 slots are the
//   bias channel: (ky0,kx0)=bias_hi, (ky0,kx1)=bias_lo, rest zero).
// w2tab [mfma m(8)][lane(64)][8]: stage-2 B-frag, K-folded: k=m*32+q*8+j;
//   k<240: combo c=k/48 (ky=c>=3, kx=c-3*ky), ch=k%48 (l=ch/3, jj=ch%3);
//   column n = out channel (n>=3 or k>=240 -> zero).
__global__ void prep_weights(const float* __restrict__ w1, const float* __restrict__ c1,
                             const float* __restrict__ b1,
                             const float* __restrict__ w2, const float* __restrict__ c2,
                             unsigned short* __restrict__ tab) {
    int e = blockIdx.x * 256 + threadIdx.x;
    if (e >= WTN) return;
    float v = 0.f;
    if (e < W2OFF) {
        int f = e >> 9, lane = (e >> 3) & 63, j = e & 7;
        int m = lane & 15, q = lane >> 4;
        int k = q * 8 + j;
        int ky = k >> 4, kx = (k >> 2) & 3, chin = k & 3;
        int ch = f * 16 + m;                 // output channel of stage 1 (= l*3+i)
        if (ch < 48) {
            if (kx < 3 && chin < 3) {
                int l = ch / 3, i = ch - l * 3;
                bool live = (ky == 0) || (kx == 0) || (kx == 1 && chin <= i);
                if (live) {
                    int g = ((l * 3 + i) * 3 + chin) * 9 + ky * 3 + kx;
                    v = (i == chin && ky == 1 && kx == 1) ? softplusf(c1[g]) : w1[g];
                }
            } else if (chin == 3 && ky == 0 && kx == 0) {
                v = b1[ch];                  // bias hi (RNE at the f2bf below)
            } else if (chin == 3 && ky == 0 && kx == 1) {
                float b  = b1[ch];
                float bh = __uint_as_float(((unsigned)f2bf(b)) << 16);
                v = b - bh;                  // bias lo residual
            }
        }
    } else {
        int e2 = e - W2OFF;
        int mf = e2 >> 9, lane = (e2 >> 3) & 63, j = e2 & 7;
        int n = lane & 15, q = lane >> 4;
        int k = mf * 32 + q * 8 + j;
        if (n < 3 && k < 240) {
            int c  = k / 48, ch = k - c * 48;
            int ky = (c >= 3) ? 1 : 0, kx = c - 3 * ky;
            int l = ch / 3, jj = ch - l * 3;
            bool live = (ky == 0) || (kx == 0) || (kx == 1 && jj <= n);
            if (live) {
                int g = ((l * 3 + n) * 3 + jj) * 9 + ky * 3 + kx;
                v = (n == jj && ky == 1 && kx == 1) ? softplusf(c2[g]) : w2[g];
            }
        }
    }
    tab[e] = f2bf(v);
}

__global__ __launch_bounds__(256, 5) void fused_mfma(
    const float* __restrict__ x,
    const float* __restrict__ res, const unsigned short* __restrict__ tab,
    float* __restrict__ out)
{
    __shared__ __align__(16) unsigned short xsb[XRow * XCol * 4];  // 3200 B
    __shared__ __align__(16) unsigned short hsb[6 * NPX * 8];      // 29376 B, [oct][px][8]

    const int tid  = threadIdx.x;
    const int b    = blockIdx.z;
    const int py0  = blockIdx.y * TS;
    const int px0  = blockIdx.x * TS;
    const int lane = tid & 63;
    const int wv   = tid >> 6;
    const int n    = lane & 15;
    const int q    = lane >> 4;

    // ---- stage x tile fp32->bf16 packed [r][c][4] ----
    // pad channel = 1.0 ALWAYS (bias tap; zero-padding applies only to real channels)
    const float* xb = x + b * NC * NH * NW;
    #pragma unroll
    for (int it = 0; it < 2; ++it) {
        unsigned p = tid + it * 256;
        if (p < XRow * XCol) {
            unsigned r = p / XCol, c = p - r * XCol;
            int gy = (int)(py0 - 2 + r), gx = (int)(px0 - 2 + c);
            bool ok = ((unsigned)gy < NH) && ((unsigned)gx < NW);
            const float* sp = xb + gy * NW + gx;
            float v0 = ok ? sp[0]           : 0.f;
            float v1 = ok ? sp[NH * NW]     : 0.f;
            float v2 = ok ? sp[2 * NH * NW] : 0.f;
            float one = 1.0f;
            unsigned ua, ub;
            asm("v_cvt_pk_bf16_f32 %0, %1, %2" : "=v"(ua) : "v"(v0), "v"(v1));
            asm("v_cvt_pk_bf16_f32 %0, %1, %2" : "=v"(ub) : "v"(v2), "v"(one));
            uint2 st; st.x = ua; st.y = ub;
            *(uint2*)(xsb + p * 4) = st;
        }
    }

    float rg; { float rv = res[0]; rg = rv > 0.f ? rv : 0.f; }

    // stage-1 A-frags (weights): coalesced 16B global loads (L2-hot table)
    bf16x8 a1f0 = *(const bf16x8*)(tab + (0 * 64 + lane) * 8);
    bf16x8 a1f1 = *(const bf16x8*)(tab + (1 * 64 + lane) * 8);
    bf16x8 a1f2 = *(const bf16x8*)(tab + (2 * 64 + lane) * 8);

    __syncthreads();  // xsb ready

    // ---- stage 1: 20 flat-px M-tiles, waves round-robin (5 each) ----
    constexpr int OSTR = NPX * 8;             // shorts per channel-octet plane
    #pragma unroll 1
    for (int t = wv; t < NT; t += 4) {
        unsigned p  = t * 16 + n;                 // this lane's pixel (B column)
        unsigned pr = p / 18, pc = p - pr * 18;
        const unsigned short* bp =
            xsb + ((pr + (q >> 1)) * XCol + pc + ((q & 1) << 1)) * 4;
        bf16x4 lo = *(const bf16x4*)bp;
        bf16x4 hi = *(const bf16x4*)(bp + 4);
        bf16x8 bf;
        #pragma unroll
        for (int j = 0; j < 4; ++j) { bf[j] = lo[j]; bf[4 + j] = hi[j]; }
        f32x4 z = {0.f, 0.f, 0.f, 0.f};
        f32x4 cc0 = __builtin_amdgcn_mfma_f32_16x16x32_bf16(a1f0, bf, z, 0, 0, 0);
        f32x4 cc1 = __builtin_amdgcn_mfma_f32_16x16x32_bf16(a1f1, bf, z, 0, 0, 0);
        f32x4 cc2 = __builtin_amdgcn_mfma_f32_16x16x32_bf16(a1f2, bf, z, 0, 0, 0);
        // mask for this pixel (h row pr-1, col pc-1 in image coords)
        float mk = (((unsigned)(py0 + (int)pr - 1) < NH) &&
                    ((unsigned)(px0 + (int)pc - 1) < NW)) ? 1.f : 0.f;
        if (p < NPX) {
            f32x4 cc[3] = {cc0, cc1, cc2};
            // channel ch = f*16 + q*4 + r -> octet plane = (q>>1) + f*2, intra = (q&1)*4
            unsigned short* hp = hsb + p * 8 + ((q & 1) << 2);
            #pragma unroll
            for (int f = 0; f < 3; ++f) {
                float e_[4];
                #pragma unroll
                for (int r = 0; r < 4; ++r) {
                    float t_ = cc[f][r];
                    e_[r] = (t_ > 0.f ? t_ : __expf(t_) - 1.f) * mk;
                }
                unsigned ua, ub;
                asm("v_cvt_pk_bf16_f32 %0, %1, %2" : "=v"(ua) : "v"(e_[0]), "v"(e_[1]));
                asm("v_cvt_pk_bf16_f32 %0, %1, %2" : "=v"(ub) : "v"(e_[2]), "v"(e_[3]));
                uint2 st; st.x = ua; st.y = ub;
                *(uint2*)(hp + ((q >> 1) + f * 2) * OSTR) = st;
            }
        }
    }

    // stage-2 B-frags (K-folded table): 8 coalesced 16B loads, before the barrier
    bf16x8 b2k[8];
    #pragma unroll
    for (int m = 0; m < 8; ++m)
        b2k[m] = *(const bf16x8*)(tab + W2OFF + (m * 64 + lane) * 8);

    // per-lane A-frag deltas (lane-constant across out rows), in [oct][px][8] layout
    int dlt[8];
    #pragma unroll
    for (int m = 0; m < 8; ++m) {
        int idx = m * 32 + q * 8;            // k-octet start for this lane
        int c   = idx / 48;                  // combo (compile-folds to cheap seq)
        int off = idx - c * 48;              // channel octet within combo (mult of 8)
        int ky  = (c >= 3) ? 1 : 0, kx = c - 3 * ky;
        // pad lanes (idx>=240): B cols zero, any in-bounds h data is fine
        dlt[m] = (idx < 240) ? ((off >> 3) * NPX + ky * 18 + kx) * 8 : 0;
    }

    __syncthreads();  // hsb ready

    // ---- stage 2: out row py, K=240 folded in 8 MFMAs, 4 accumulators ----
    float* ob = out + b * NC * NH * NW;
    #pragma unroll 1
    for (int s = 0; s < 4; ++s) {
        int py = wv + s * 4;                 // out row 0..15
        const unsigned short* hbase = hsb + (py * 18 + n) * 8;
        f32x4 acc[4];
        #pragma unroll
        for (int a = 0; a < 4; ++a) acc[a] = (f32x4){0.f, 0.f, 0.f, 0.f};
        #pragma unroll
        for (int m = 0; m < 8; ++m) {
            bf16x8 af = *(const bf16x8*)(hbase + dlt[m]);
            acc[m & 3] = __builtin_amdgcn_mfma_f32_16x16x32_bf16(af, b2k[m], acc[m & 3], 0, 0, 0);
        }
        if (n < 3) {                          // lanes with a real out channel
            f32x4 t0, t1, sum;
            #pragma unroll
            for (int r = 0; r < 4; ++r) {
                t0[r] = acc[0][r] + acc[1][r];
                t1[r] = acc[2][r] + acc[3][r];
                sum[r] = t0[r] + t1[r];
            }
            int gy = py0 + py;
            const float* xp = xb + n * NH * NW + gy * NW + px0;
            float*       op = ob + n * NH * NW + gy * NW + px0;
            float4 xv = *(const float4*)(xp + q * 4);
            float4 o;
            o.x = sum[0] * (1.f / 16.f) + rg * xv.x;
            o.y = sum[1] * (1.f / 16.f) + rg * xv.y;
            o.z = sum[2] * (1.f / 16.f) + rg * xv.z;
            o.w = sum[3] * (1.f / 16.f) + rg * xv.w;
            *(float4*)(op + q * 4) = o;
        }
    }
}

extern "C" void kernel_launch(void* const* d_in, const int* in_sizes, int n_in,
                              void* d_out, int out_size, void* d_ws, size_t ws_size,
                              hipStream_t stream) {
    (void)in_sizes; (void)n_in; (void)out_size; (void)ws_size;
    const float* x   = (const float*)d_in[0];
    const float* w1  = (const float*)d_in[1];
    const float* c1  = (const float*)d_in[2];
    const float* b1  = (const float*)d_in[3];
    const float* w2  = (const float*)d_in[4];
    const float* c2  = (const float*)d_in[5];
    const float* res = (const float*)d_in[6];
    float* out = (float*)d_out;
    unsigned short* tab = (unsigned short*)d_ws;   // 11264 B of swizzled bf16 weights

    hipLaunchKernelGGL(prep_weights, dim3((WTN + 255) / 256), dim3(256), 0, stream,
                       w1, c1, b1, w2, c2, tab);
    hipLaunchKernelGGL(fused_mfma, dim3(NW / TS, NH / TS, 64), dim3(256), 0, stream,
                       x, res, tab, out);
}

// Round 3
// 100.833 us; speedup vs baseline: 1.0409x; 1.0100x over previous
//
#include <hip/hip_runtime.h>
#include <hip/hip_bf16.h>
#include <math.h>

// BasicBlockA via MFMA (bf16 in, fp32 accum). R15 = R14 + stage-2 dy-packing + mask fold:
//   Stage 2: old code used 3/16 N columns (out ch) and re-spanned K=240 per out row
//   (4 row-iters x 8 MFMAs). Now N column n = ch*4 + dy packs 4 output rows (12 live
//   cols); K = (rho=h-row-offset 0..4, kx, ch48), 14 live (rho,kx) pairs x 48ch padded
//   to 64 slots/pair -> 28 MFMAs total (vs 32), ONE epilogue pass (vs 4). Pad K-slots:
//   A reads valid finite h (vb1 clamps to plane q), B columns zero. A-frag addr =
//   vb/vb1 + compile-time literal -> ds_read_b128 with imm offset, no runtime dlt.
//   B-frags stream in-loop from L2/L1-hot table (frees 32 VGPRs).
//   Stage 1: border mask folded as 6 packed-u32 cndmasks (was 12 fp muls/iter).
// R14: cvt_pk bf16 packing; bias1 folded into MFMA via pad channel (hi+lo split).
// R13: hsb [oct(6)][px(306)][8ch] conflict-free layout.
// Layouts (m89/m91): A[m=lane&15][k=q*8+j], B[k=q*8+j][n=lane&15], C col=lane&15 row=q*4+reg.

typedef short bf16x8 __attribute__((ext_vector_type(8)));
typedef short bf16x4 __attribute__((ext_vector_type(4)));
typedef float f32x4  __attribute__((ext_vector_type(4)));

namespace {
constexpr int NC = 3, NH = 128, NW = 128;
constexpr int TS = 16;                        // output tile 16x16
constexpr int XRow = 20, XCol = 20;           // xs bf16 [20][20][4]
constexpr int NPX = 306;                      // h pixels: 17 rows x 18 cols (flat)
constexpr int NT  = 20;                       // stage-1 M-tiles (20*16 = 320 slots)
constexpr int W2OFF = 1536;                   // shorts: w1tab 3*64*8
constexpr int NM2   = 28;                     // stage-2 MFMAs (14 pairs x 2)
constexpr int WTN   = 1536 + NM2 * 512;       // 15872 shorts = 31744 B in d_ws
}

__device__ __forceinline__ float softplusf(float v) {
    return v > 20.f ? v : log1pf(expf(v));
}
__device__ __forceinline__ unsigned short f2bf(float v) {   // RNE (prep only)
    __hip_bfloat16 h = __float2bfloat16(v);
    return *reinterpret_cast<unsigned short*>(&h);
}

// w1tab [f(3)][lane(64)][8]: stage-1 A-frag; m=lane&15 -> channel ch=f*16+m (=l*3+i),
//   k=q*8+j -> ky=k>>4, kx=(k>>2)&3, chin=k&3 (kx==3 zero-pad; chin==3 slots are the
//   bias channel: (ky0,kx0)=bias_hi, (ky0,kx1)=bias_lo, rest zero).
// w2tab [m(28)][lane(64)][8]: stage-2 B-frag, dy-packed:
//   pair p = m>>1 -> (rho = p/3, kx = p-3*rho), p in 0..13 (rho 0..4; p=12,13 -> rho=4).
//   chOct = (m&1)*4 + q; ch48 = chOct*8 + j (chOct>=6 -> pad, zero).
//   column n: ch = n>>2 (out channel, >=3 -> zero), dy = n&3 (output row offset).
//   ky = rho - dy; live iff ky in {0,1} and causal mask allows.
__global__ void prep_weights(const float* __restrict__ w1, const float* __restrict__ c1,
                             const float* __restrict__ b1,
                             const float* __restrict__ w2, const float* __restrict__ c2,
                             unsigned short* __restrict__ tab) {
    int e = blockIdx.x * 256 + threadIdx.x;
    if (e >= WTN) return;
    float v = 0.f;
    if (e < W2OFF) {
        int f = e >> 9, lane = (e >> 3) & 63, j = e & 7;
        int m = lane & 15, q = lane >> 4;
        int k = q * 8 + j;
        int ky = k >> 4, kx = (k >> 2) & 3, chin = k & 3;
        int ch = f * 16 + m;                 // output channel of stage 1 (= l*3+i)
        if (ch < 48) {
            if (kx < 3 && chin < 3) {
                int l = ch / 3, i = ch - l * 3;
                bool live = (ky == 0) || (kx == 0) || (kx == 1 && chin <= i);
                if (live) {
                    int g = ((l * 3 + i) * 3 + chin) * 9 + ky * 3 + kx;
                    v = (i == chin && ky == 1 && kx == 1) ? softplusf(c1[g]) : w1[g];
                }
            } else if (chin == 3 && ky == 0 && kx == 0) {
                v = b1[ch];                  // bias hi (RNE at the f2bf below)
            } else if (chin == 3 && ky == 0 && kx == 1) {
                float b  = b1[ch];
                float bh = __uint_as_float(((unsigned)f2bf(b)) << 16);
                v = b - bh;                  // bias lo residual
            }
        }
    } else {
        int e2 = e - W2OFF;                  // 0..14335
        int mf = e2 >> 9;                    // 0..27
        int lane = (e2 >> 3) & 63, j = e2 & 7;
        int n = lane & 15, q = lane >> 4;
        int p  = mf >> 1, hh = mf & 1;
        int rho = p / 3, kx = p - rho * 3;   // p=12,13 -> rho=4, kx=0,1
        int chOct = hh * 4 + q;
        int ch = n >> 2, dy = n & 3;
        if (ch < 3 && chOct < 6) {
            int ch48 = chOct * 8 + j;        // 0..47
            int l = ch48 / 3, jj = ch48 - l * 3;
            int ky = rho - dy;
            if (ky == 0 || ky == 1) {
                bool live = (ky == 0) || (kx == 0) || (kx == 1 && jj <= ch);
                if (live) {
                    int g = ((l * 3 + ch) * 3 + jj) * 9 + ky * 3 + kx;
                    v = (ch == jj && ky == 1 && kx == 1) ? softplusf(c2[g]) : w2[g];
                }
            }
        }
    }
    tab[e] = f2bf(v);
}

__global__ __launch_bounds__(256, 5) void fused_mfma(
    const float* __restrict__ x,
    const float* __restrict__ res, const unsigned short* __restrict__ tab,
    float* __restrict__ out)
{
    __shared__ __align__(16) unsigned short xsb[XRow * XCol * 4];  // 3200 B
    __shared__ __align__(16) unsigned short hsb[6 * NPX * 8];      // 29376 B, [oct][px][8]

    const int tid  = threadIdx.x;
    const int b    = blockIdx.z;
    const int py0  = blockIdx.y * TS;
    const int px0  = blockIdx.x * TS;
    const int lane = tid & 63;
    const int wv   = tid >> 6;
    const int n    = lane & 15;
    const int q    = lane >> 4;

    // ---- stage x tile fp32->bf16 packed [r][c][4] ----
    // pad channel = 1.0 ALWAYS (bias tap; zero-padding applies only to real channels)
    const float* xb = x + b * NC * NH * NW;
    #pragma unroll
    for (int it = 0; it < 2; ++it) {
        unsigned p = tid + it * 256;
        if (p < XRow * XCol) {
            unsigned r = p / XCol, c = p - r * XCol;
            int gy = (int)(py0 - 2 + r), gx = (int)(px0 - 2 + c);
            bool ok = ((unsigned)gy < NH) && ((unsigned)gx < NW);
            const float* sp = xb + gy * NW + gx;
            float v0 = ok ? sp[0]           : 0.f;
            float v1 = ok ? sp[NH * NW]     : 0.f;
            float v2 = ok ? sp[2 * NH * NW] : 0.f;
            float one = 1.0f;
            unsigned ua, ub;
            asm("v_cvt_pk_bf16_f32 %0, %1, %2" : "=v"(ua) : "v"(v0), "v"(v1));
            asm("v_cvt_pk_bf16_f32 %0, %1, %2" : "=v"(ub) : "v"(v2), "v"(one));
            uint2 st; st.x = ua; st.y = ub;
            *(uint2*)(xsb + p * 4) = st;
        }
    }

    float rg; { float rv = res[0]; rg = rv > 0.f ? rv : 0.f; }

    // stage-1 A-frags (weights): coalesced 16B global loads (L2-hot table)
    bf16x8 a1f0 = *(const bf16x8*)(tab + (0 * 64 + lane) * 8);
    bf16x8 a1f1 = *(const bf16x8*)(tab + (1 * 64 + lane) * 8);
    bf16x8 a1f2 = *(const bf16x8*)(tab + (2 * 64 + lane) * 8);

    __syncthreads();  // xsb ready

    // ---- stage 1: 20 flat-px M-tiles, waves round-robin (5 each) ----
    constexpr int OSTR = NPX * 8;             // shorts per channel-octet plane
    #pragma unroll 1
    for (int t = wv; t < NT; t += 4) {
        unsigned p  = t * 16 + n;                 // this lane's pixel (B column)
        unsigned pr = p / 18, pc = p - pr * 18;
        const unsigned short* bp =
            xsb + ((pr + (q >> 1)) * XCol + pc + ((q & 1) << 1)) * 4;
        bf16x4 lo = *(const bf16x4*)bp;
        bf16x4 hi = *(const bf16x4*)(bp + 4);
        bf16x8 bf;
        #pragma unroll
        for (int j = 0; j < 4; ++j) { bf[j] = lo[j]; bf[4 + j] = hi[j]; }
        f32x4 z = {0.f, 0.f, 0.f, 0.f};
        f32x4 cc0 = __builtin_amdgcn_mfma_f32_16x16x32_bf16(a1f0, bf, z, 0, 0, 0);
        f32x4 cc1 = __builtin_amdgcn_mfma_f32_16x16x32_bf16(a1f1, bf, z, 0, 0, 0);
        f32x4 cc2 = __builtin_amdgcn_mfma_f32_16x16x32_bf16(a1f2, bf, z, 0, 0, 0);
        // mask for this pixel (h row pr-1, col pc-1 in image coords)
        bool mok = (((unsigned)(py0 + (int)pr - 1) < NH) &&
                    ((unsigned)(px0 + (int)pc - 1) < NW));
        if (p < NPX) {
            f32x4 cc[3] = {cc0, cc1, cc2};
            // channel ch = f*16 + q*4 + r -> octet plane = (q>>1) + f*2, intra = (q&1)*4
            unsigned short* hp = hsb + p * 8 + ((q & 1) << 2);
            #pragma unroll
            for (int f = 0; f < 3; ++f) {
                float e_[4];
                #pragma unroll
                for (int r = 0; r < 4; ++r) {
                    float t_ = cc[f][r];
                    e_[r] = t_ > 0.f ? t_ : __expf(t_) - 1.f;
                }
                unsigned ua, ub;
                asm("v_cvt_pk_bf16_f32 %0, %1, %2" : "=v"(ua) : "v"(e_[0]), "v"(e_[1]));
                asm("v_cvt_pk_bf16_f32 %0, %1, %2" : "=v"(ub) : "v"(e_[2]), "v"(e_[3]));
                uint2 st; st.x = mok ? ua : 0u; st.y = mok ? ub : 0u;
                *(uint2*)(hp + ((q >> 1) + f * 2) * OSTR) = st;
            }
        }
    }

    __syncthreads();  // hsb ready

    // ---- stage 2: dy-packed, 28 MFMAs cover 4 out rows (wv*4+dy) x 16 px x 3 ch ----
    // A-frag addr for MFMA m: (m&1 ? vb1 : vb) + (rho*18+kx)*8 shorts (imm offset).
    // vb  = plane q, h pixel (wv*4)*18 + n;  vb1 = vb + 4 planes for q<2 (live chOct
    // 4,5), else vb (pad: valid finite data x zero B columns).
    const unsigned short* vb  = hsb + q * OSTR + (wv * 4 * 18 + n) * 8;
    const unsigned short* vb1 = (q < 2) ? (vb + 4 * OSTR) : vb;

    f32x4 acc[4];
    #pragma unroll
    for (int a = 0; a < 4; ++a) acc[a] = (f32x4){0.f, 0.f, 0.f, 0.f};

    constexpr int P_RHO[14] = {0,0,0,1,1,1,2,2,2,3,3,3,4,4};
    constexpr int P_KX[14]  = {0,1,2,0,1,2,0,1,2,0,1,2,0,1};
    #pragma unroll
    for (int m = 0; m < NM2; ++m) {
        int pp = m >> 1;
        const unsigned short* ap = (m & 1) ? vb1 : vb;
        bf16x8 af = *(const bf16x8*)(ap + (P_RHO[pp] * 18 + P_KX[pp]) * 8);
        bf16x8 bf2 = *(const bf16x8*)(tab + W2OFF + (m * 64 + lane) * 8);
        acc[m & 3] = __builtin_amdgcn_mfma_f32_16x16x32_bf16(af, bf2, acc[m & 3], 0, 0, 0);
    }

    float* ob = out + b * NC * NH * NW;
    {
        f32x4 t0, t1, sum;
        #pragma unroll
        for (int r = 0; r < 4; ++r) {
            t0[r] = acc[0][r] + acc[1][r];
            t1[r] = acc[2][r] + acc[3][r];
            sum[r] = t0[r] + t1[r];
        }
        if (n < 12) {                         // col n = ch*4 + dy
            int ch = n >> 2, dy = n & 3;
            int gy = py0 + wv * 4 + dy;
            const float* xp = xb + ch * NH * NW + gy * NW + px0;
            float*       op = ob + ch * NH * NW + gy * NW + px0;
            float4 xv = *(const float4*)(xp + q * 4);
            float4 o;
            o.x = sum[0] * (1.f / 16.f) + rg * xv.x;
            o.y = sum[1] * (1.f / 16.f) + rg * xv.y;
            o.z = sum[2] * (1.f / 16.f) + rg * xv.z;
            o.w = sum[3] * (1.f / 16.f) + rg * xv.w;
            *(float4*)(op + q * 4) = o;
        }
    }
}

extern "C" void kernel_launch(void* const* d_in, const int* in_sizes, int n_in,
                              void* d_out, int out_size, void* d_ws, size_t ws_size,
                              hipStream_t stream) {
    (void)in_sizes; (void)n_in; (void)out_size; (void)ws_size;
    const float* x   = (const float*)d_in[0];
    const float* w1  = (const float*)d_in[1];
    const float* c1  = (const float*)d_in[2];
    const float* b1  = (const float*)d_in[3];
    const float* w2  = (const float*)d_in[4];
    const float* c2  = (const float*)d_in[5];
    const float* res = (const float*)d_in[6];
    float* out = (float*)d_out;
    unsigned short* tab = (unsigned short*)d_ws;   // 31744 B of swizzled bf16 weights

    hipLaunchKernelGGL(prep_weights, dim3((WTN + 255) / 256), dim3(256), 0, stream,
                       w1, c1, b1, w2, c2, tab);
    hipLaunchKernelGGL(fused_mfma, dim3(NW / TS, NH / TS, 64), dim3(256), 0, stream,
                       x, res, tab, out);
}